// Round 16
// baseline (152.282 us; speedup 1.0000x reference)
//
#include <hip/hip_runtime.h>
#include <hip/hip_bf16.h>

#define LEN 128
#define NB 32
#define NC 16
#define NU 16
#define NK 5
#define KC 80          // (k,c) pairs
#define KCP 96         // padded K for stage2

typedef unsigned int uint32;
typedef unsigned short ushort16;
typedef __attribute__((ext_vector_type(8))) short bf16x8;
typedef __attribute__((ext_vector_type(4))) float f32x4;

#define MFMA(a, b, c) __builtin_amdgcn_mfma_f32_16x16x32_bf16(a, b, c, 0, 0, 0)

// XOR swizzle of the 16B-unit index within a 64-dword row (16 units).
#define SIG(r) (((r) & 15) ^ (((r) >> 3) & 15))

static __device__ inline ushort16 f2bf(float f) {
    union { float f; uint32 u; } v; v.f = f;
    uint32 u = v.u;
    uint32 r = (u + 0x7fffu + ((u >> 16) & 1u)) >> 16;   // RNE
    return (ushort16)r;
}
static __device__ inline uint32 pkbf(float a, float b) {   // low=a, high=b (verified r0-r15)
    return (uint32)f2bf(a) | ((uint32)f2bf(b) << 16);
}
static __device__ inline bf16x8 frag16(const void* p) {    // 16B-aligned
    return *(const bf16x8*)p;
}

// ---------------- kconst: constant operands -> MFMA fragment layout (670 blocks) ----------------
__global__ __launch_bounds__(256) void kconst(const float* __restrict__ coefs,
                                              const float* __restrict__ cheb1,
                                              const float* __restrict__ cheb2,
                                              ushort16* __restrict__ cheb1F,
                                              ushort16* __restrict__ cheb2F,
                                              ushort16* __restrict__ coefF) {
    int i = blockIdx.x * 256 + threadIdx.x;      // 0..171519
    if (i < 81920) {
        int j = i & 7, lane = (i >> 3) & 63, ks = (i >> 9) & 3, nt = i >> 11;
        int kp = nt * 16 + (lane & 15);
        int k = kp >> 7, p = kp & 127;
        int h = ks * 32 + ((lane >> 4) << 3) + j;
        cheb1F[i] = f2bf(cheb1[(k * LEN + h) * LEN + p]);
    } else if (i < 163840) {
        int i2 = i - 81920;
        int j = i2 & 7, lane = (i2 >> 3) & 63, t = i2 >> 9;
        int ks = t % 20, nt = t / 20;
        int q = nt * 16 + (lane & 15);
        int lw = ks * 32 + ((lane >> 4) << 3) + j;
        int l = lw >> 7, w = lw & 127;
        cheb2F[i2] = f2bf(cheb2[(l * LEN + w) * LEN + q]);
    } else {
        int i3 = i - 163840;
        int j = i3 & 7, lane = (i3 >> 3) & 63, t = i3 >> 9;
        int ks = t % 3, nt = t / 3;
        int lu = nt * 16 + (lane & 15);
        int l = lu >> 4, u = lu & 15;
        int kc = ks * 32 + ((lane >> 4) << 3) + j;
        int k = kc >> 4, c = kc & 15;
        coefF[i3] = (kc < KC) ? f2bf(coefs[((k * NK + l) * NC + c) * NU + u]) : (ushort16)0;
    }
}

// ---------------- kfuse: per (c, bl, z) block — x transpose + HALF the k1 GEMM.
// z in {0,1} splits the 8 N-segments into 2 blocks of 4 -> 1024 blocks (2x the
// parallelism; per-block serial chain halves). The duplicate x transpose is
// L3-hot (x = 32MB, just read by the twin block). All math verbatim r15.
__global__ __launch_bounds__(256, 3) void kfuse(const float* __restrict__ x,
                                                const ushort16* __restrict__ cheb1F,
                                                ushort16* __restrict__ t1, int b0) {
    __shared__ __align__(16) uint32 Xs[128 * 64];  // 32KB
    __shared__ __align__(16) uint32 Bs[64 * 64];   // 16KB bounce
    const int c = blockIdx.x, bl = blockIdx.y, z = blockIdx.z;
    const int b = b0 + bl;
    const int tid = threadIdx.x;
    const int lane = tid & 63, wm = tid >> 6;      // wave = m-quarter
    const int m16 = lane & 15, g = lane >> 4;

    // phase 1: transpose + cvt x -> Xs
    {
        const float* xp = x + (size_t)(b * NC + c) * (LEN * LEN);
        int w = tid & 127, hg = tid >> 7;
        #pragma unroll
        for (int uu = 0; uu < 8; ++uu) {
            int u = hg * 8 + uu;
            uint4 d;
            uint32* dp = (uint32*)&d;
            #pragma unroll
            for (int t = 0; t < 4; ++t) {
                int h2 = u * 4 + t;
                dp[t] = pkbf(xp[(2 * h2) * LEN + w], xp[(2 * h2 + 1) * LEN + w]);
            }
            *(uint4*)(Xs + w * 64 + ((u ^ SIG(w)) << 2)) = d;
        }
    }
    __syncthreads();

    // phase 2: 4 segments of 64 kp (this block's half: ns = z*4 + s)
    for (int s = 0; s < 4; ++s) {
        const int ns = z * 4 + s;
        f32x4 acc[2][4];
        #pragma unroll
        for (int mi = 0; mi < 2; ++mi)
            #pragma unroll
            for (int ni = 0; ni < 4; ++ni) acc[mi][ni] = (f32x4)0.f;

        #pragma unroll
        for (int ks = 0; ks < 4; ++ks) {
            bf16x8 Af[2], Bf[4];
            #pragma unroll
            for (int mi = 0; mi < 2; ++mi) {
                int wrow = (wm * 2 + mi) * 16 + m16;
                Af[mi] = frag16(Xs + wrow * 64 + (((ks * 4 + g) ^ SIG(wrow)) << 2));
            }
            #pragma unroll
            for (int ni = 0; ni < 4; ++ni) {
                int nt = 8 + ns * 4 + ni;
                Bf[ni] = frag16(cheb1F + ((size_t)(nt * 4 + ks) * 64 + lane) * 8);
            }
            #pragma unroll
            for (int mi = 0; mi < 2; ++mi)
                #pragma unroll
                for (int ni = 0; ni < 4; ++ni)
                    acc[mi][ni] = MFMA(Af[mi], Bf[ni], acc[mi][ni]);
        }

        if (s) __syncthreads();   // prev pass's readout done before overwriting Bs

        // bounce: D element (m = w = wm*32+mi*16+g*4+r, n = rr = ni*16+m16)
        #pragma unroll
        for (int ni = 0; ni < 4; ++ni)
            #pragma unroll
            for (int mi = 0; mi < 2; ++mi) {
                int rr = ni * 16 + m16;
                int wu = wm * 32 + mi * 16 + g * 4;       // ushort col (w)
                uint2 d;
                d.x = pkbf(acc[mi][ni][0], acc[mi][ni][1]);
                d.y = pkbf(acc[mi][ni][2], acc[mi][ni][3]);
                int u = wu >> 3;
                *(uint2*)(Bs + rr * 64 + ((u ^ SIG(rr)) << 2) + ((wu >> 1) & 3)) = d;
            }
        __syncthreads();

        // read-out + coalesced store (256B runs); kp = 128 + ns*64 + rr
        #pragma unroll
        for (int i = 0; i < 4; ++i) {
            int n = tid + i * 256;                 // 0..1023
            int rr = n >> 4, wsg = n & 15;
            uint4 v = *(const uint4*)(Bs + rr * 64 + ((wsg ^ SIG(rr)) << 2));
            int kp = 128 + ns * 64 + rr;
            int k = kp >> 7, p = kp & 127;
            *(uint4*)(t1 + ((size_t)((bl * LEN + p) * KC + k * NC + c)) * LEN + wsg * 8) = v;
        }
    }
}

// ---------------- k2: per (p, bl) block (1 p-slice, 32KB LDS, 5 blocks/CU)
// Ts rows kc 0..15 (k=0, T_0=I) staged DIRECTLY from x; rows 16..79 from t1.
// stage2: s[w][lu] = Ts[w][kc] x coefF (K=96, padded); stage3: out[u][q] =
// A3[u][lw] x cheb2F, ks 4..19 (l=0 identity added in epilogue). (r15 verbatim)
__global__ __launch_bounds__(256, 5) void k2_mfma(const ushort16* __restrict__ t1,
                                                  const float* __restrict__ x,
                                                  const ushort16* __restrict__ coefF,
                                                  const ushort16* __restrict__ cheb2F,
                                                  float* __restrict__ out, int b0) {
    __shared__ __align__(16) uint32 sm[128 * 64];   // 32KB: Ts [w][kc units swz]; A3 (16x648 ush) aliases
    const int p = blockIdx.x, bl = blockIdx.y, b = b0 + bl;
    const int tid = threadIdx.x;
    const int lane = tid & 63, wave = tid >> 6;
    const int n16 = lane & 15, g = lane >> 4;

    // issue t1 global loads FIRST (kc rows 16..79 -> pair cols a2 = 8..39)
    const uint32* t1u = (const uint32*)(t1 + (size_t)(bl * LEN + p) * (KC * LEN));
    uint4 Av[2], Bv[2];
    #pragma unroll
    for (int i = 0; i < 2; ++i) {
        int it = tid + i * 256;              // 0..511, all active
        int a2 = 8 + (it >> 4), wq = it & 15;
        const uint32* src = t1u + a2 * 128 + wq * 4;
        Av[i] = *(const uint4*)(src);
        Bv[i] = *(const uint4*)(src + 64);
    }
    // k=0 rows from x: pair j = tid>>5 (c = 2j, 2j+1), w0 = (tid&31)*4
    float4 X0, X1;
    {
        int j = tid >> 5, w0 = (tid & 31) << 2;
        const float* xb = x + ((size_t)(b * NC) * LEN + p) * LEN;
        const float* xa = xb + (size_t)(2 * j) * (LEN * LEN);
        X0 = *(const float4*)(xa + w0);
        X1 = *(const float4*)(xa + LEN * LEN + w0);
    }
    // zero K-pad (dw 40..47 = units 10,11) while loads are in flight
    #pragma unroll
    for (int i = 0; i < 4; ++i) {
        int idx = tid + i * 256;             // 0..1023
        int row = idx >> 3, d = idx & 7;
        int u = 10 + (d >> 2);
        sm[row * 64 + ((u ^ SIG(row)) << 2) + (d & 3)] = 0;
    }
    // write k=0 dword-cols (a2 = j = 0..7): sm[w][col j] = pk(x[2j][p][w], x[2j+1][p][w])
    {
        int j = tid >> 5, w0 = (tid & 31) << 2;
        const float* f0 = (const float*)&X0;
        const float* f1 = (const float*)&X1;
        int u0 = j >> 2, lo = j & 3;
        #pragma unroll
        for (int r = 0; r < 4; ++r) {
            int row = w0 + r;
            sm[row * 64 + ((u0 ^ SIG(row)) << 2) + lo] = pkbf(f0[r], f1[r]);
        }
    }
    // transpose t1 kc-pairs into swizzled rows (verified shift/mask merges)
    #pragma unroll
    for (int i = 0; i < 2; ++i) {
        int it = tid + i * 256;
        int a2 = 8 + (it >> 4), wq = it & 15;
        const uint32* av = (const uint32*)&Av[i];
        const uint32* bv = (const uint32*)&Bv[i];
        int u = a2 >> 2, lo = a2 & 3;
        #pragma unroll
        for (int j = 0; j < 4; ++j) {
            int r0 = wq * 8 + 2 * j, r1 = r0 + 1;
            sm[r0 * 64 + ((u ^ SIG(r0)) << 2) + lo] = (av[j] & 0xffffu) | (bv[j] << 16);
            sm[r1 * 64 + ((u ^ SIG(r1)) << 2) + lo] = (av[j] >> 16) | (bv[j] & 0xffff0000u);
        }
    }
    __syncthreads();

    // ---- stage2: rows w = wave*32 + mi*16 + n16
    f32x4 acc[2][5];
    #pragma unroll
    for (int mi = 0; mi < 2; ++mi)
        #pragma unroll
        for (int ni = 0; ni < 5; ++ni) acc[mi][ni] = (f32x4)0.f;

    #pragma unroll
    for (int ks = 0; ks < 3; ++ks) {
        bf16x8 Af[2], Bf[5];
        #pragma unroll
        for (int mi = 0; mi < 2; ++mi) {
            int row = wave * 32 + mi * 16 + n16;
            Af[mi] = frag16(sm + row * 64 + (((ks * 4 + g) ^ SIG(row)) << 2));
        }
        #pragma unroll
        for (int ni = 0; ni < 5; ++ni)
            Bf[ni] = frag16(coefF + ((size_t)(ni * 3 + ks) * 64 + lane) * 8);
        #pragma unroll
        for (int mi = 0; mi < 2; ++mi)
            #pragma unroll
            for (int ni = 0; ni < 5; ++ni)
                acc[mi][ni] = MFMA(Af[mi], Bf[ni], acc[mi][ni]);
    }
    __syncthreads();   // Ts reads done; A3 may overwrite

    // s -> A3: row u = n16 (16 rows, stride 648 ushort), col l*128+w
    {
        ushort16* A3 = (ushort16*)sm;
        #pragma unroll
        for (int mi = 0; mi < 2; ++mi)
            #pragma unroll
            for (int ni = 0; ni < 5; ++ni) {
                int wcol = wave * 32 + mi * 16 + g * 4;
                uint2 d;
                d.x = pkbf(acc[mi][ni][0], acc[mi][ni][1]);
                d.y = pkbf(acc[mi][ni][2], acc[mi][ni][3]);
                *(uint2*)(A3 + n16 * 648 + ni * 128 + wcol) = d;
            }
    }
    __syncthreads();

    // ---- stage3: M=16 (u), wave owns 32 q. Skip l=0 (identity): ks 4..19 only.
    const ushort16* A3r = (const ushort16*)sm;
    f32x4 c3[2];
    c3[0] = (f32x4)0.f; c3[1] = (f32x4)0.f;
    #pragma unroll 4
    for (int ks = 4; ks < 20; ++ks) {
        bf16x8 Aa = frag16(A3r + n16 * 648 + ks * 32 + g * 8);
        #pragma unroll
        for (int nt = 0; nt < 2; ++nt) {
            bf16x8 Bb = frag16(cheb2F + ((size_t)((wave * 2 + nt) * 20 + ks) * 64 + lane) * 8);
            c3[nt] = MFMA(Aa, Bb, c3[nt]);
        }
    }

    #pragma unroll
    for (int nt = 0; nt < 2; ++nt)
        #pragma unroll
        for (int r = 0; r < 4; ++r) {
            int u = g * 4 + r;
            int q = wave * 32 + nt * 16 + n16;
            // l=0 identity contribution: + s[u][w=q] (bf16 in A3 col q)
            uint32 bf = ((uint32)A3r[u * 648 + q]) << 16;
            float l0 = __uint_as_float(bf);
            out[(((size_t)(b * NU + u)) * LEN + p) * LEN + q] = c3[nt][r] + l0;
        }
}

extern "C" void kernel_launch(void* const* d_in, const int* in_sizes, int n_in,
                              void* d_out, int out_size, void* d_ws, size_t ws_size,
                              hipStream_t stream) {
    const float* x     = (const float*)d_in[0];
    const float* coefs = (const float*)d_in[1];
    const float* cheb1 = (const float*)d_in[2];
    const float* cheb2 = (const float*)d_in[3];
    float* out = (float*)d_out;

    const size_t aux_bytes = 163840 + 163840 + 15360;          // cheb1F + cheb2F + coefF
    size_t off = (ws_size - aux_bytes) & ~(size_t)255;
    ushort16* cheb1F = (ushort16*)((char*)d_ws + off);
    ushort16* cheb2F = cheb1F + 81920;
    ushort16* coefF  = cheb2F + 81920;
    ushort16* t1 = (ushort16*)d_ws;

    const size_t per_b = (size_t)LEN * KC * LEN * sizeof(ushort16);        // 2.62 MB
    int chunk = (int)(off / per_b);
    if (chunk < 1) chunk = 1;
    if (chunk > NB) chunk = NB;

    hipLaunchKernelGGL(kconst, dim3(670), dim3(256), 0, stream,
                       coefs, cheb1, cheb2, cheb1F, cheb2F, coefF);
    for (int b0 = 0; b0 < NB; b0 += chunk) {
        int cb = (NB - b0 < chunk) ? (NB - b0) : chunk;
        hipLaunchKernelGGL(kfuse, dim3(NC, cb, 2), dim3(256), 0, stream,
                           x, cheb1F, t1, b0);
        hipLaunchKernelGGL(k2_mfma, dim3(LEN, cb), dim3(256), 0, stream,
                           t1, x, coefF, cheb2F, out, b0);
    }
}